// Round 11
// baseline (272.687 us; speedup 1.0000x reference)
//
#include <hip/hip_runtime.h>
#include <math.h>

#define N_NODES 20000
#define M_PAD   20032            // 64-row padded for MFMA row tiles
#define E_EDGES 640000
#define ET (E_EDGES + N_NODES)   // edges + self loops
#define IN_CH 256
#define D1 128                   // H1*C1 = 8*16
#define D2 256                   // H2*C2 = 1*256
#define BPAIRS 4096
#define NEG 0.2f
#define LOG2E 1.4426950408889634f

#define NB_HIST   128
#define CHUNK     ((ET + NB_HIST - 1) / NB_HIST)   // 5157
#define HALF_BINS 10000

#define MARK_BLOCKS  (2 * BPAIRS / 256)           // 32
#define WT_BLOCKS    32                           // 4 matrices x 8 64x64 tiles
#define XCONV_BLOCKS (M_PAD * IN_CH / 4 / 4 / 256) // 1252 (ILP-4)

#define G1X (M_PAD / 64)          // 313
#define G1Y (D1 / 64)             // 2
#define G1_BLOCKS (G1X * G1Y)     // 626
#define SCAT_BLOCKS ((ET + 255) / 256)  // 2579

#if __has_builtin(__builtin_amdgcn_exp2f)
#define EXP2F(x) __builtin_amdgcn_exp2f(x)
#else
#define EXP2F(x) exp2f(x)
#endif

typedef __bf16 bf16x8 __attribute__((ext_vector_type(8)));
typedef float  f32x4  __attribute__((ext_vector_type(4)));
typedef float  f32x2  __attribute__((ext_vector_type(2)));
typedef unsigned short u16x4 __attribute__((ext_vector_type(4)));

__device__ __forceinline__ unsigned short f2b(float f) {
    unsigned int u = __float_as_uint(f);
    unsigned int r = u + 0x7FFFu + ((u >> 16) & 1u);   // RNE
    return (unsigned short)(r >> 16);
}
__device__ __forceinline__ f32x2 up2(unsigned int u) {
    f32x2 r;
    r.x = __uint_as_float(u << 16);
    r.y = __uint_as_float(u & 0xFFFF0000u);
    return r;
}
__device__ __forceinline__ f32x2 lrelu2(f32x2 s) {
    return __builtin_elementwise_max(s, s * NEG);
}
__device__ __forceinline__ float lrelu(float s) { return fmaxf(s, NEG * s); }

__device__ __forceinline__ void unpack8(uint4 u, float* v) {
    v[0] = __uint_as_float(u.x << 16); v[1] = __uint_as_float(u.x & 0xFFFF0000u);
    v[2] = __uint_as_float(u.y << 16); v[3] = __uint_as_float(u.y & 0xFFFF0000u);
    v[4] = __uint_as_float(u.z << 16); v[5] = __uint_as_float(u.z & 0xFFFF0000u);
    v[6] = __uint_as_float(u.w << 16); v[7] = __uint_as_float(u.w & 0xFFFF0000u);
}

// ------- fused prep: LDS histogram + mark + LDS-tiled W^T + x conversion ----

__global__ __launch_bounds__(256) void prep_kernel(
        const float* __restrict__ gnn_x,
        const float* __restrict__ Wl1, const float* __restrict__ Wr1,
        const float* __restrict__ Wl2, const float* __restrict__ Wr2,
        const int* __restrict__ edge_dst,
        const int* __restrict__ a1_raw, const int* __restrict__ a2_raw,
        unsigned short* __restrict__ xb,
        unsigned short* __restrict__ wt1l, unsigned short* __restrict__ wt1r,
        unsigned short* __restrict__ wt2l, unsigned short* __restrict__ wt2r,
        int* __restrict__ cb,              // [NB_HIST][N_NODES] block counts
        int* __restrict__ rank,
        int* __restrict__ mark) {
    __shared__ int lc[HALF_BINS];          // 40 KB (reused as transpose tile)
    int bid = blockIdx.x;
    if (bid < NB_HIST) {
        // per-chunk LDS histogram; rank = order within (chunk, dst)
        int ebeg = bid * CHUNK;
        int eend = min(ebeg + CHUNK, ET);
#pragma unroll 1
        for (int half = 0; half < 2; half++) {
            int lo = half * HALF_BINS;
            for (int i = threadIdx.x; i < HALF_BINS; i += 256) lc[i] = 0;
            __syncthreads();
            for (int e = ebeg + threadIdx.x; e < eend; e += 256) {
                int dst = (e < E_EDGES) ? edge_dst[e] : (e - E_EDGES);
                int d = dst - lo;
                if (0 <= d && d < HALF_BINS) rank[e] = atomicAdd(&lc[d], 1);
            }
            __syncthreads();
            for (int i = threadIdx.x; i < HALF_BINS; i += 256)
                cb[(size_t)bid * N_NODES + lo + i] = lc[i];
            __syncthreads();
        }
    } else if (bid < NB_HIST + MARK_BLOCKS) {
        // mark dst nodes needed by the classifier (sentinel value 1)
        int idx = (bid - NB_HIST) * 256 + threadIdx.x;   // 0..8191
        __shared__ int stride_s;
        if (threadIdx.x == 0) {
            bool i64 = true;
            for (int i = 1; i < 63; i += 2) i64 = i64 && (a1_raw[i] == 0);
            stride_s = i64 ? 2 : 1;
        }
        __syncthreads();
        int stride = stride_s;
        if (idx < BPAIRS) mark[a1_raw[(long)idx * stride]] = 1;
        else mark[a2_raw[(long)(idx - BPAIRS) * stride]] = 1;
    } else if (bid < NB_HIST + MARK_BLOCKS + WT_BLOCKS) {
        // W [K x N] -> Wt [N x K] via 64x64 LDS tile; coalesced both sides
        unsigned short* tile = (unsigned short*)lc;      // 64 x 65 bf16
        int t = bid - NB_HIST - MARK_BLOCKS;             // 0..31
        int m = t >> 3;                                  // matrix 0..3
        int tt = t & 7;                                  // tile in matrix
        const float* W;
        unsigned short* Wt;
        int K, N;
        if (m == 0)      { W = Wl1; Wt = wt1l; K = IN_CH; N = D1; }
        else if (m == 1) { W = Wr1; Wt = wt1r; K = IN_CH; N = D1; }
        else if (m == 2) { W = Wl2; Wt = wt2l; K = D1; N = D2; }
        else             { W = Wr2; Wt = wt2r; K = D1; N = D2; }
        int ntn = N >> 6;                                // n-tiles per matrix
        int k0 = (tt / ntn) << 6;
        int n0 = (tt % ntn) << 6;
        int c = threadIdx.x & 63;
        int rr = threadIdx.x >> 6;                       // 0..3
#pragma unroll
        for (int ch = 0; ch < 16; ch++) {
            int row = rr * 16 + ch;
            tile[row * 65 + c] = f2b(W[(size_t)(k0 + row) * N + n0 + c]);
        }
        __syncthreads();
#pragma unroll
        for (int ch = 0; ch < 16; ch++) {
            int n = rr * 16 + ch;
            Wt[(size_t)(n0 + n) * K + k0 + c] = tile[c * 65 + n];
        }
    } else {
        // x -> bf16 with zero row padding; ILP-4, NT load
        int tid = (bid - NB_HIST - MARK_BLOCKS - WT_BLOCKS) * 256
                + threadIdx.x;
        const int NQ = M_PAD * IN_CH / 4;  // total float4 groups
        int q0 = tid * 4;
#pragma unroll
        for (int j = 0; j < 4; j++) {
            int qi = q0 + j;
            if (qi >= NQ) break;
            int e0 = qi * 4;
            int row = e0 >> 8;             // / IN_CH
            u16x4 o;
            if (row < N_NODES) {
                f32x4 v = __builtin_nontemporal_load((const f32x4*)(gnn_x + e0));
                o.x = f2b(v.x); o.y = f2b(v.y); o.z = f2b(v.z); o.w = f2b(v.w);
            } else {
                o.x = o.y = o.z = o.w = 0;
            }
            *(u16x4*)(xb + e0) = o;
        }
    }
}

// ---- per-dst exclusive prefix over hist blocks; writes total to count ------

__global__ __launch_bounds__(256) void repprefix_kernel(
        int* __restrict__ cb, int* __restrict__ count) {
    int dst = blockIdx.x * 256 + threadIdx.x;
    if (dst >= N_NODES) return;
    int run = 0;
#pragma unroll 4
    for (int r = 0; r < NB_HIST; r++) {
        size_t idx = (size_t)r * N_NODES + dst;
        int c = cb[idx];
        cb[idx] = run;
        run += c;
    }
    count[dst] = run;
}

// ---------------- CSR scan ----------------

__global__ __launch_bounds__(1024) void scan_kernel(const int* __restrict__ count,
                                                    int* __restrict__ offsets) {
    const int PER = 20;
    int t = threadIdx.x;
    int base = t * PER;
    int local[PER];
    int sum = 0;
#pragma unroll
    for (int i = 0; i < PER; i++) {
        int idx = base + i;
        int v = (idx < N_NODES) ? count[idx] : 0;
        local[i] = sum;
        sum += v;
    }
    int lane = t & 63, wave = t >> 6;
    int s = sum;
#pragma unroll
    for (int off = 1; off < 64; off <<= 1) {
        int x = __shfl_up(s, off);
        if (lane >= off) s += x;
    }
    __shared__ int wsum[16];
    __shared__ int wpre[16];
    if (lane == 63) wsum[wave] = s;
    __syncthreads();
    if (t == 0) {
        int acc = 0;
        for (int w = 0; w < 16; w++) { wpre[w] = acc; acc += wsum[w]; }
        offsets[N_NODES] = acc;  // == ET
    }
    __syncthreads();
    int thread_excl = wpre[wave] + (s - sum);
#pragma unroll
    for (int i = 0; i < PER; i++) {
        int idx = base + i;
        if (idx < N_NODES) offsets[idx] = thread_excl + local[i];
    }
}

// ---------------- dual GEMM tile (device body, 16 cols/wave) ----------------

template <int K>
__device__ __forceinline__ void dual_gemm_tile(
        const unsigned short* __restrict__ A,
        const unsigned short* __restrict__ Wtl,
        const unsigned short* __restrict__ Wtr,
        const float* __restrict__ bl, const float* __restrict__ br,
        unsigned short* __restrict__ Yl, unsigned short* __restrict__ Yr,
        int M, int NOUT, int bx, int by) {
    const int NK = K / 32;
    int wave = threadIdx.x >> 6;
    int lane = threadIdx.x & 63;
    int row0 = bx * 64;
    int col0 = (by * 4 + wave) * 16;
    int rsub = lane & 15;
    int koff = (lane >> 4) * 8;

    const unsigned short* ap  = A   + (size_t)(row0 + rsub) * K + koff;
    const unsigned short* bpl = Wtl + (size_t)(col0 + rsub) * K + koff;
    const unsigned short* bpr = Wtr + (size_t)(col0 + rsub) * K + koff;

    bf16x8 bfl[NK], bfr[NK];
#pragma unroll
    for (int kb = 0; kb < NK; kb++) {
        bfl[kb] = *(const bf16x8*)(bpl + kb * 32);
        bfr[kb] = *(const bf16x8*)(bpr + kb * 32);
    }

    f32x4 l0 = {0.f, 0.f, 0.f, 0.f};
    f32x4 l1 = l0, l2 = l0, l3 = l0, r0 = l0, r1 = l0, r2 = l0, r3 = l0;

#pragma unroll
    for (int kb = 0; kb < NK; kb++) {
        int off = kb * 32;
        bf16x8 a0 = *(const bf16x8*)(ap + off);
        bf16x8 a1 = *(const bf16x8*)(ap + 16 * K + off);
        bf16x8 a2 = *(const bf16x8*)(ap + 32 * K + off);
        bf16x8 a3 = *(const bf16x8*)(ap + 48 * K + off);
        l0 = __builtin_amdgcn_mfma_f32_16x16x32_bf16(a0, bfl[kb], l0, 0, 0, 0);
        r0 = __builtin_amdgcn_mfma_f32_16x16x32_bf16(a0, bfr[kb], r0, 0, 0, 0);
        l1 = __builtin_amdgcn_mfma_f32_16x16x32_bf16(a1, bfl[kb], l1, 0, 0, 0);
        r1 = __builtin_amdgcn_mfma_f32_16x16x32_bf16(a1, bfr[kb], r1, 0, 0, 0);
        l2 = __builtin_amdgcn_mfma_f32_16x16x32_bf16(a2, bfl[kb], l2, 0, 0, 0);
        r2 = __builtin_amdgcn_mfma_f32_16x16x32_bf16(a2, bfr[kb], r2, 0, 0, 0);
        l3 = __builtin_amdgcn_mfma_f32_16x16x32_bf16(a3, bfl[kb], l3, 0, 0, 0);
        r3 = __builtin_amdgcn_mfma_f32_16x16x32_bf16(a3, bfr[kb], r3, 0, 0, 0);
    }

    int colg = col0 + rsub;
    float bvl = bl[colg];
    float bvr = br[colg];
    int rbase = row0 + (lane >> 4) * 4;
#pragma unroll
    for (int t = 0; t < 4; t++) {
        f32x4 al = (t == 0) ? l0 : (t == 1) ? l1 : (t == 2) ? l2 : l3;
        f32x4 ar = (t == 0) ? r0 : (t == 1) ? r1 : (t == 2) ? r2 : r3;
#pragma unroll
        for (int r = 0; r < 4; r++) {
            int row = rbase + t * 16 + r;
            if (row < M) {
                Yl[(size_t)row * NOUT + colg] = f2b(al[r] + bvl);
                Yr[(size_t)row * NOUT + colg] = f2b(ar[r] + bvr);
            }
        }
    }
}

// ---------------- merged: gemm1 (layer-1 dual GEMM) + edge scatter ----------

__global__ __launch_bounds__(256) void gemm1_scatter_kernel(
        const unsigned short* __restrict__ A,
        const unsigned short* __restrict__ Wtl,
        const unsigned short* __restrict__ Wtr,
        const float* __restrict__ bl, const float* __restrict__ br,
        unsigned short* __restrict__ Yl, unsigned short* __restrict__ Yr,
        const int* __restrict__ edge_src, const int* __restrict__ edge_dst,
        const int* __restrict__ rank, const int* __restrict__ offsets,
        const int* __restrict__ cb, int* __restrict__ sorted_src) {
    int bid = blockIdx.x;
    if (bid < G1_BLOCKS) {
        dual_gemm_tile<IN_CH>(A, Wtl, Wtr, bl, br, Yl, Yr,
                              N_NODES, D1, bid % G1X, bid / G1X);
    } else {
        int e = (bid - G1_BLOCKS) * 256 + threadIdx.x;
        if (e >= ET) return;
        int dst = (e < E_EDGES) ? edge_dst[e] : (e - E_EDGES);
        int src = (e < E_EDGES) ? edge_src[e] : (e - E_EDGES);
        int rep = e / CHUNK;
        sorted_src[offsets[dst] + cb[(size_t)rep * N_NODES + dst] + rank[e]] = src;
    }
}

// ---------------- gemm2: 32 cols/wave (16 MFMA per 4 A-loads) ---------------

template <int K>
__global__ __launch_bounds__(256) void dual_gemm_w32_kernel(
        const unsigned short* __restrict__ A,
        const unsigned short* __restrict__ Wtl,
        const unsigned short* __restrict__ Wtr,
        const float* __restrict__ bl, const float* __restrict__ br,
        unsigned short* __restrict__ Yl, unsigned short* __restrict__ Yr,
        int M, int NOUT) {
    const int NK = K / 32;
    int wave = threadIdx.x >> 6;
    int lane = threadIdx.x & 63;
    int row0 = blockIdx.x * 64;
    int col0 = blockIdx.y * 128 + wave * 32;
    int rsub = lane & 15;
    int koff = (lane >> 4) * 8;

    const unsigned short* ap = A + (size_t)(row0 + rsub) * K + koff;

    bf16x8 bfl[2][NK], bfr[2][NK];
#pragma unroll
    for (int c = 0; c < 2; c++) {
        const unsigned short* bpl = Wtl + (size_t)(col0 + c * 16 + rsub) * K + koff;
        const unsigned short* bpr = Wtr + (size_t)(col0 + c * 16 + rsub) * K + koff;
#pragma unroll
        for (int kb = 0; kb < NK; kb++) {
            bfl[c][kb] = *(const bf16x8*)(bpl + kb * 32);
            bfr[c][kb] = *(const bf16x8*)(bpr + kb * 32);
        }
    }

    f32x4 accl[2][4], accr[2][4];
#pragma unroll
    for (int c = 0; c < 2; c++)
#pragma unroll
        for (int t = 0; t < 4; t++) {
            accl[c][t] = (f32x4){0.f, 0.f, 0.f, 0.f};
            accr[c][t] = (f32x4){0.f, 0.f, 0.f, 0.f};
        }

#pragma unroll
    for (int kb = 0; kb < NK; kb++) {
        int off = kb * 32;
        bf16x8 a[4];
        a[0] = *(const bf16x8*)(ap + off);
        a[1] = *(const bf16x8*)(ap + 16 * K + off);
        a[2] = *(const bf16x8*)(ap + 32 * K + off);
        a[3] = *(const bf16x8*)(ap + 48 * K + off);
#pragma unroll
        for (int t = 0; t < 4; t++) {
#pragma unroll
            for (int c = 0; c < 2; c++) {
                accl[c][t] = __builtin_amdgcn_mfma_f32_16x16x32_bf16(
                    a[t], bfl[c][kb], accl[c][t], 0, 0, 0);
                accr[c][t] = __builtin_amdgcn_mfma_f32_16x16x32_bf16(
                    a[t], bfr[c][kb], accr[c][t], 0, 0, 0);
            }
        }
    }

    int rbase = row0 + (lane >> 4) * 4;
#pragma unroll
    for (int c = 0; c < 2; c++) {
        int colg = col0 + c * 16 + rsub;
        float bvl = bl[colg];
        float bvr = br[colg];
#pragma unroll
        for (int t = 0; t < 4; t++) {
#pragma unroll
            for (int r = 0; r < 4; r++) {
                int row = rbase + t * 16 + r;
                if (row < M) {
                    Yl[(size_t)row * NOUT + colg] = f2b(accl[c][t][r] + bvl);
                    Yr[(size_t)row * NOUT + colg] = f2b(accr[c][t][r] + bvr);
                }
            }
        }
    }
}

// ---------------- layer 1 aggregation (quarter-wave per edge, prefetch-2) ---

__global__ __launch_bounds__(256) void aggregate1_kernel(
        const unsigned short* __restrict__ xl1, const unsigned short* __restrict__ xr1,
        const float* __restrict__ att1, const float* __restrict__ bias1,
        const int* __restrict__ offsets, const int* __restrict__ sorted_src,
        unsigned short* __restrict__ x1) {
    int wave = threadIdx.x >> 6;
    int lane = threadIdx.x & 63;
    int q = lane >> 4;                 // quarter 0..3
    int ql = lane & 15;
    int dst = blockIdx.x * 4 + wave;
    if (dst >= M_PAD) return;
    int c0 = ql * 8;
    if (dst >= N_NODES) {              // zero pad rows for the next GEMM
        if (q == 0) {
            uint4 z; z.x = z.y = z.z = z.w = 0;
            *(uint4*)(x1 + (size_t)dst * D1 + c0) = z;
        }
        return;
    }

    uint4 xu = *(const uint4*)(xr1 + (size_t)dst * D1 + c0);
    f32x2 xr[4] = {up2(xu.x), up2(xu.y), up2(xu.z), up2(xu.w)};
    float4 aa0 = *(const float4*)(att1 + c0);
    float4 aa1 = *(const float4*)(att1 + c0 + 4);
    f32x2 att[4];
    att[0].x = aa0.x * LOG2E; att[0].y = aa0.y * LOG2E;
    att[1].x = aa0.z * LOG2E; att[1].y = aa0.w * LOG2E;
    att[2].x = aa1.x * LOG2E; att[2].y = aa1.y * LOG2E;
    att[3].x = aa1.z * LOG2E; att[3].y = aa1.w * LOG2E;

    int beg = offsets[dst], end = offsets[dst + 1];
    const unsigned short* base = xl1 + c0;

    float l = 0.f;
    f32x2 acc[4] = {{0.f,0.f},{0.f,0.f},{0.f,0.f},{0.f,0.f}};

    int i = beg;
    int s0 = sorted_src[min(i + q, end - 1)];
    uint4 g0 = *(const uint4*)(base + (size_t)s0 * D1);
    bool more1 = (i + 4) < end;
    uint4 g1;
    if (more1) {
        int s1 = sorted_src[min(i + 4 + q, end - 1)];
        g1 = *(const uint4*)(base + (size_t)s1 * D1);
    }
    while (true) {
        bool more2 = (i + 8) < end;
        uint4 g2;
        if (more2) {
            int s2 = sorted_src[min(i + 8 + q, end - 1)];
            g2 = *(const uint4*)(base + (size_t)s2 * D1);
        }
        bool act = (i + q) < end;
        f32x2 v0 = up2(g0.x), v1 = up2(g0.y), v2 = up2(g0.z), v3 = up2(g0.w);
        f32x2 p2 = att[0] * lrelu2(v0 + xr[0]);
        p2 += att[1] * lrelu2(v1 + xr[1]);
        p2 += att[2] * lrelu2(v2 + xr[2]);
        p2 += att[3] * lrelu2(v3 + xr[3]);
        float p = p2.x + p2.y;
        p += __shfl_xor(p, 1);          // head reduce (2 lanes/head)
        float w = act ? EXP2F(p) : 0.f;
        l += w;
        acc[0] += w * v0; acc[1] += w * v1; acc[2] += w * v2; acc[3] += w * v3;
        if (!more1) break;
        i += 4;
        g0 = g1; g1 = g2; more1 = more2;
    }
    // merge quarters
    l += __shfl_xor(l, 16);
    l += __shfl_xor(l, 32);
#pragma unroll
    for (int j = 0; j < 4; j++) {
        f32x2 t;
        t.x = __shfl_xor(acc[j].x, 16); t.y = __shfl_xor(acc[j].y, 16);
        acc[j] += t;
        t.x = __shfl_xor(acc[j].x, 32); t.y = __shfl_xor(acc[j].y, 32);
        acc[j] += t;
    }
    if (q == 0) {
        float inv = 1.f / l;
        float4 bb0 = *(const float4*)(bias1 + c0);
        float4 bb1 = *(const float4*)(bias1 + c0 + 4);
        unsigned short o[8];
        o[0] = f2b(fmaxf(acc[0].x * inv + bb0.x, 0.f));
        o[1] = f2b(fmaxf(acc[0].y * inv + bb0.y, 0.f));
        o[2] = f2b(fmaxf(acc[1].x * inv + bb0.z, 0.f));
        o[3] = f2b(fmaxf(acc[1].y * inv + bb0.w, 0.f));
        o[4] = f2b(fmaxf(acc[2].x * inv + bb1.x, 0.f));
        o[5] = f2b(fmaxf(acc[2].y * inv + bb1.y, 0.f));
        o[6] = f2b(fmaxf(acc[3].x * inv + bb1.z, 0.f));
        o[7] = f2b(fmaxf(acc[3].y * inv + bb1.w, 0.f));
        uint4 ov;
        ov.x = (unsigned int)o[0] | ((unsigned int)o[1] << 16);
        ov.y = (unsigned int)o[2] | ((unsigned int)o[3] << 16);
        ov.z = (unsigned int)o[4] | ((unsigned int)o[5] << 16);
        ov.w = (unsigned int)o[6] | ((unsigned int)o[7] << 16);
        *(uint4*)(x1 + (size_t)dst * D1 + c0) = ov;
    }
}

// ---------------- layer 2 aggregation (masked to classifier-needed dsts) ----

__global__ __launch_bounds__(256) void aggregate2_kernel(
        const unsigned short* __restrict__ xl2, const unsigned short* __restrict__ xr2,
        const float* __restrict__ att2, const float* __restrict__ bias2,
        const int* __restrict__ offsets, const int* __restrict__ sorted_src,
        const int* __restrict__ mark,
        float* __restrict__ x2) {
    int wave = threadIdx.x >> 6;
    int lane = threadIdx.x & 63;
    int half = lane >> 5;
    int hl = lane & 31;
    int dst = blockIdx.x * 4 + wave;
    if (dst >= N_NODES) return;
    if (mark[dst] != 1) return;        // classifier never reads this row
    int c0 = hl * 8;

    float xr[8], att[8];
    unpack8(*(const uint4*)(xr2 + (size_t)dst * D2 + c0), xr);
#pragma unroll
    for (int j = 0; j < 8; j++) att[j] = att2[c0 + j] * LOG2E;
    int beg = offsets[dst], end = offsets[dst + 1];

    float l = 0.f;
    float acc[8];
#pragma unroll
    for (int j = 0; j < 8; j++) acc[j] = 0.f;

    int i = beg;
    for (; i + 4 <= end; i += 4) {
        int sA = sorted_src[i + half];
        int sB = sorted_src[i + 2 + half];
        float vA[8], vB[8];
        unpack8(*(const uint4*)(xl2 + (size_t)sA * D2 + c0), vA);
        unpack8(*(const uint4*)(xl2 + (size_t)sB * D2 + c0), vB);
        float pA = 0.f, pB = 0.f;
#pragma unroll
        for (int j = 0; j < 8; j++) pA = fmaf(att[j], lrelu(vA[j] + xr[j]), pA);
#pragma unroll
        for (int j = 0; j < 8; j++) pB = fmaf(att[j], lrelu(vB[j] + xr[j]), pB);
        pA += __shfl_xor(pA, 1);  pB += __shfl_xor(pB, 1);
        pA += __shfl_xor(pA, 2);  pB += __shfl_xor(pB, 2);
        pA += __shfl_xor(pA, 4);  pB += __shfl_xor(pB, 4);
        pA += __shfl_xor(pA, 8);  pB += __shfl_xor(pB, 8);
        pA += __shfl_xor(pA, 16); pB += __shfl_xor(pB, 16);
        float wA = EXP2F(pA), wB = EXP2F(pB);
        l += wA + wB;
#pragma unroll
        for (int j = 0; j < 8; j++) acc[j] += wA * vA[j] + wB * vB[j];
    }
    for (; i + 2 <= end; i += 2) {
        int sA = sorted_src[i + half];
        float vA[8];
        unpack8(*(const uint4*)(xl2 + (size_t)sA * D2 + c0), vA);
        float pA = 0.f;
#pragma unroll
        for (int j = 0; j < 8; j++) pA = fmaf(att[j], lrelu(vA[j] + xr[j]), pA);
        pA += __shfl_xor(pA, 1);
        pA += __shfl_xor(pA, 2);
        pA += __shfl_xor(pA, 4);
        pA += __shfl_xor(pA, 8);
        pA += __shfl_xor(pA, 16);
        float wA = EXP2F(pA);
        l += wA;
#pragma unroll
        for (int j = 0; j < 8; j++) acc[j] += wA * vA[j];
    }
    if (i < end && half == 0) {
        int sA = sorted_src[i];
        float vA[8];
        unpack8(*(const uint4*)(xl2 + (size_t)sA * D2 + c0), vA);
        float pA = 0.f;
#pragma unroll
        for (int j = 0; j < 8; j++) pA = fmaf(att[j], lrelu(vA[j] + xr[j]), pA);
        pA += __shfl_xor(pA, 1);
        pA += __shfl_xor(pA, 2);
        pA += __shfl_xor(pA, 4);
        pA += __shfl_xor(pA, 8);
        pA += __shfl_xor(pA, 16);
        float wA = EXP2F(pA);
        l += wA;
#pragma unroll
        for (int j = 0; j < 8; j++) acc[j] += wA * vA[j];
    }
    // merge halves
    l += __shfl_xor(l, 32);
#pragma unroll
    for (int j = 0; j < 8; j++) acc[j] += __shfl_xor(acc[j], 32);
    if (half == 0) {
        float inv = 1.f / l;
        float4 o0, o1;
        o0.x = acc[0] * inv + bias2[c0 + 0];
        o0.y = acc[1] * inv + bias2[c0 + 1];
        o0.z = acc[2] * inv + bias2[c0 + 2];
        o0.w = acc[3] * inv + bias2[c0 + 3];
        o1.x = acc[4] * inv + bias2[c0 + 4];
        o1.y = acc[5] * inv + bias2[c0 + 5];
        o1.z = acc[6] * inv + bias2[c0 + 6];
        o1.w = acc[7] * inv + bias2[c0 + 7];
        *(float4*)(x2 + (size_t)dst * D2 + c0) = o0;
        *(float4*)(x2 + (size_t)dst * D2 + c0 + 4) = o1;
    }
}

// ---------------- classifier ----------------

__global__ __launch_bounds__(256) void classifier_kernel(
        const float* __restrict__ vanilla_x, const float* __restrict__ x2,
        const int* __restrict__ a1_raw, const int* __restrict__ a2_raw,
        const float* __restrict__ Wc, const float* __restrict__ bc,
        float* __restrict__ out) {
    int b = blockIdx.x;
    int t = threadIdx.x;

    __shared__ int stride_s;
    if (t == 0) {
        bool i64 = true;
        for (int i = 1; i < 63; i += 2) i64 = i64 && (a1_raw[i] == 0);
        stride_s = i64 ? 2 : 1;
    }
    __syncthreads();
    int stride = stride_s;
    int a1 = a1_raw[(long)b * stride];
    int a2 = a2_raw[(long)b * stride];

    float s = vanilla_x[a1 * IN_CH + t] * Wc[t]
            + vanilla_x[a2 * IN_CH + t] * Wc[IN_CH + t]
            + x2[a1 * D2 + t] * Wc[2 * IN_CH + t]
            + x2[a2 * D2 + t] * Wc[3 * IN_CH + t];
    s += __shfl_xor(s, 1);
    s += __shfl_xor(s, 2);
    s += __shfl_xor(s, 4);
    s += __shfl_xor(s, 8);
    s += __shfl_xor(s, 16);
    s += __shfl_xor(s, 32);
    __shared__ float part[4];
    if ((t & 63) == 0) part[t >> 6] = s;
    __syncthreads();
    if (t == 0) out[b] = part[0] + part[1] + part[2] + part[3] + bc[0];
}

// ---------------- launch ----------------

extern "C" void kernel_launch(void* const* d_in, const int* in_sizes, int n_in,
                              void* d_out, int out_size, void* d_ws, size_t ws_size,
                              hipStream_t stream) {
    const float* gnn_x     = (const float*)d_in[0];
    const float* vanilla_x = (const float*)d_in[1];
    const int*   edge_src  = (const int*)d_in[2];
    const int*   edge_dst  = (const int*)d_in[3];
    const int*   a1_idx    = (const int*)d_in[4];
    const int*   a2_idx    = (const int*)d_in[5];
    const float* Wl1   = (const float*)d_in[6];
    const float* bl1   = (const float*)d_in[7];
    const float* Wr1   = (const float*)d_in[8];
    const float* br1   = (const float*)d_in[9];
    const float* att1  = (const float*)d_in[10];
    const float* bias1 = (const float*)d_in[11];
    const float* Wl2   = (const float*)d_in[12];
    const float* bl2   = (const float*)d_in[13];
    const float* Wr2   = (const float*)d_in[14];
    const float* br2   = (const float*)d_in[15];
    const float* att2  = (const float*)d_in[16];
    const float* bias2 = (const float*)d_in[17];
    const float* Wc    = (const float*)d_in[18];
    const float* bc    = (const float*)d_in[19];
    float* out = (float*)d_out;

    // workspace layout
    char* p = (char*)d_ws;
    unsigned short* xb   = (unsigned short*)p; p += (size_t)M_PAD * IN_CH * 2;
    unsigned short* x1b  = (unsigned short*)p; p += (size_t)M_PAD * D1 * 2;
    unsigned short* xl1b = (unsigned short*)p; p += (size_t)N_NODES * D1 * 2;
    unsigned short* xr1b = (unsigned short*)p; p += (size_t)N_NODES * D1 * 2;
    unsigned short* xl2b = (unsigned short*)p; p += (size_t)N_NODES * D2 * 2;
    unsigned short* xr2b = (unsigned short*)p; p += (size_t)N_NODES * D2 * 2;
    unsigned short* wt1l = (unsigned short*)p; p += (size_t)D1 * IN_CH * 2;
    unsigned short* wt1r = (unsigned short*)p; p += (size_t)D1 * IN_CH * 2;
    unsigned short* wt2l = (unsigned short*)p; p += (size_t)D2 * D1 * 2;
    unsigned short* wt2r = (unsigned short*)p; p += (size_t)D2 * D1 * 2;
    float* x2 = (float*)p; p += (size_t)N_NODES * D2 * 4;
    int* count      = (int*)p; p += (size_t)N_NODES * 4;
    int* mark       = (int*)p; p += (size_t)N_NODES * 4;
    int* offsets    = (int*)p; p += (size_t)(N_NODES + 4) * 4;
    int* rank       = (int*)p; p += (size_t)ET * 4;
    int* sorted_src = (int*)p; p += (size_t)ET * 4;
    // cb aliases xl2b: alive prep..scatter; xl2b written by gemm2 afterwards.
    int* cb = (int*)xl2b;

    prep_kernel<<<NB_HIST + MARK_BLOCKS + WT_BLOCKS + XCONV_BLOCKS,
                  256, 0, stream>>>(
        gnn_x, Wl1, Wr1, Wl2, Wr2, edge_dst, a1_idx, a2_idx,
        xb, wt1l, wt1r, wt2l, wt2r, cb, rank, mark);
    repprefix_kernel<<<(N_NODES + 255) / 256, 256, 0, stream>>>(cb, count);
    scan_kernel<<<1, 1024, 0, stream>>>(count, offsets);

    // layer-1 dual GEMM + edge scatter (independent; one dispatch)
    gemm1_scatter_kernel<<<G1_BLOCKS + SCAT_BLOCKS, 256, 0, stream>>>(
        xb, wt1l, wt1r, bl1, br1, xl1b, xr1b,
        edge_src, edge_dst, rank, offsets, cb, sorted_src);

    aggregate1_kernel<<<M_PAD / 4, 256, 0, stream>>>(
        xl1b, xr1b, att1, bias1, offsets, sorted_src, x1b);

    // layer 2: 32-col-per-wave dual GEMM
    dim3 g2(M_PAD / 64, D2 / 128);   // (313, 2)
    dual_gemm_w32_kernel<D1><<<g2, 256, 0, stream>>>(
        x1b, wt2l, wt2r, bl2, br2, xl2b, xr2b, N_NODES, D2);
    aggregate2_kernel<<<(N_NODES + 3) / 4, 256, 0, stream>>>(
        xl2b, xr2b, att2, bias2, offsets, sorted_src, mark, x2);

    // classifier
    classifier_kernel<<<BPAIRS, 256, 0, stream>>>(
        vanilla_x, x2, a1_idx, a2_idx, Wc, bc, out);
}

// Round 12
// 262.248 us; speedup vs baseline: 1.0398x; 1.0398x over previous
//
#include <hip/hip_runtime.h>
#include <math.h>

#define N_NODES 20000
#define M_PAD   20032            // 64-row padded for MFMA row tiles
#define E_EDGES 640000
#define ET (E_EDGES + N_NODES)   // edges + self loops
#define IN_CH 256
#define D1 128                   // H1*C1 = 8*16
#define D2 256                   // H2*C2 = 1*256
#define BPAIRS 4096
#define NEG 0.2f
#define LOG2E 1.4426950408889634f

#define NB_HIST   128
#define CHUNK     ((ET + NB_HIST - 1) / NB_HIST)   // 5157
#define HALF_BINS 10000

#define WT_BLOCKS    32                           // 4 matrices x 8 64x64 tiles
#define XCONV_BLOCKS (M_PAD * IN_CH / 4 / 4 / 256) // 1252 (ILP-4)

#define G1X (M_PAD / 64)          // 313
#define G1Y (D1 / 64)             // 2
#define G1_BLOCKS (G1X * G1Y)     // 626
#define SCAT_BLOCKS ((ET + 255) / 256)  // 2579

#if __has_builtin(__builtin_amdgcn_exp2f)
#define EXP2F(x) __builtin_amdgcn_exp2f(x)
#else
#define EXP2F(x) exp2f(x)
#endif

typedef __bf16 bf16x8 __attribute__((ext_vector_type(8)));
typedef float  f32x4  __attribute__((ext_vector_type(4)));
typedef float  f32x2  __attribute__((ext_vector_type(2)));
typedef unsigned short u16x4 __attribute__((ext_vector_type(4)));

__device__ __forceinline__ unsigned short f2b(float f) {
    unsigned int u = __float_as_uint(f);
    unsigned int r = u + 0x7FFFu + ((u >> 16) & 1u);   // RNE
    return (unsigned short)(r >> 16);
}
__device__ __forceinline__ f32x2 up2(unsigned int u) {
    f32x2 r;
    r.x = __uint_as_float(u << 16);
    r.y = __uint_as_float(u & 0xFFFF0000u);
    return r;
}
__device__ __forceinline__ f32x2 lrelu2(f32x2 s) {
    return __builtin_elementwise_max(s, s * NEG);
}
__device__ __forceinline__ float lrelu(float s) { return fmaxf(s, NEG * s); }

__device__ __forceinline__ void unpack8(uint4 u, float* v) {
    v[0] = __uint_as_float(u.x << 16); v[1] = __uint_as_float(u.x & 0xFFFF0000u);
    v[2] = __uint_as_float(u.y << 16); v[3] = __uint_as_float(u.y & 0xFFFF0000u);
    v[4] = __uint_as_float(u.z << 16); v[5] = __uint_as_float(u.z & 0xFFFF0000u);
    v[6] = __uint_as_float(u.w << 16); v[7] = __uint_as_float(u.w & 0xFFFF0000u);
}

// ------- fused prep: LDS histogram + LDS-tiled W^T + x conversion -----------

__global__ __launch_bounds__(256) void prep_kernel(
        const float* __restrict__ gnn_x,
        const float* __restrict__ Wl1, const float* __restrict__ Wr1,
        const float* __restrict__ Wl2, const float* __restrict__ Wr2,
        const int* __restrict__ edge_dst,
        unsigned short* __restrict__ xb,
        unsigned short* __restrict__ wt1l, unsigned short* __restrict__ wt1r,
        unsigned short* __restrict__ wt2l, unsigned short* __restrict__ wt2r,
        int* __restrict__ cb,              // [NB_HIST][N_NODES] block counts
        int* __restrict__ rank) {
    __shared__ int lc[HALF_BINS];          // 40 KB (reused as transpose tile)
    int bid = blockIdx.x;
    if (bid < NB_HIST) {
        // per-chunk LDS histogram; rank = order within (chunk, dst)
        int ebeg = bid * CHUNK;
        int eend = min(ebeg + CHUNK, ET);
#pragma unroll 1
        for (int half = 0; half < 2; half++) {
            int lo = half * HALF_BINS;
            for (int i = threadIdx.x; i < HALF_BINS; i += 256) lc[i] = 0;
            __syncthreads();
            for (int e = ebeg + threadIdx.x; e < eend; e += 256) {
                int dst = (e < E_EDGES) ? edge_dst[e] : (e - E_EDGES);
                int d = dst - lo;
                if (0 <= d && d < HALF_BINS) rank[e] = atomicAdd(&lc[d], 1);
            }
            __syncthreads();
            for (int i = threadIdx.x; i < HALF_BINS; i += 256)
                cb[(size_t)bid * N_NODES + lo + i] = lc[i];
            __syncthreads();
        }
    } else if (bid < NB_HIST + WT_BLOCKS) {
        // W [K x N] -> Wt [N x K] via 64x64 LDS tile; coalesced both sides
        unsigned short* tile = (unsigned short*)lc;      // 64 x 65 bf16
        int t = bid - NB_HIST;                           // 0..31
        int m = t >> 3;                                  // matrix 0..3
        int tt = t & 7;                                  // tile in matrix
        const float* W;
        unsigned short* Wt;
        int K, N;
        if (m == 0)      { W = Wl1; Wt = wt1l; K = IN_CH; N = D1; }
        else if (m == 1) { W = Wr1; Wt = wt1r; K = IN_CH; N = D1; }
        else if (m == 2) { W = Wl2; Wt = wt2l; K = D1; N = D2; }
        else             { W = Wr2; Wt = wt2r; K = D1; N = D2; }
        int ntn = N >> 6;                                // n-tiles per matrix
        int k0 = (tt / ntn) << 6;
        int n0 = (tt % ntn) << 6;
        int c = threadIdx.x & 63;
        int rr = threadIdx.x >> 6;                       // 0..3
#pragma unroll
        for (int ch = 0; ch < 16; ch++) {
            int row = rr * 16 + ch;
            tile[row * 65 + c] = f2b(W[(size_t)(k0 + row) * N + n0 + c]);
        }
        __syncthreads();
#pragma unroll
        for (int ch = 0; ch < 16; ch++) {
            int n = rr * 16 + ch;
            Wt[(size_t)(n0 + n) * K + k0 + c] = tile[c * 65 + n];
        }
    } else {
        // x -> bf16 with zero row padding; ILP-4, NT load
        int tid = (bid - NB_HIST - WT_BLOCKS) * 256 + threadIdx.x;
        const int NQ = M_PAD * IN_CH / 4;  // total float4 groups
        int q0 = tid * 4;
#pragma unroll
        for (int j = 0; j < 4; j++) {
            int qi = q0 + j;
            if (qi >= NQ) break;
            int e0 = qi * 4;
            int row = e0 >> 8;             // / IN_CH
            u16x4 o;
            if (row < N_NODES) {
                f32x4 v = __builtin_nontemporal_load((const f32x4*)(gnn_x + e0));
                o.x = f2b(v.x); o.y = f2b(v.y); o.z = f2b(v.z); o.w = f2b(v.w);
            } else {
                o.x = o.y = o.z = o.w = 0;
            }
            *(u16x4*)(xb + e0) = o;
        }
    }
}

// ---- per-dst exclusive prefix over hist blocks; writes total to count ------

__global__ __launch_bounds__(256) void repprefix_kernel(
        int* __restrict__ cb, int* __restrict__ count) {
    int dst = blockIdx.x * 256 + threadIdx.x;
    if (dst >= N_NODES) return;
    int run = 0;
#pragma unroll 4
    for (int r = 0; r < NB_HIST; r++) {
        size_t idx = (size_t)r * N_NODES + dst;
        int c = cb[idx];
        cb[idx] = run;
        run += c;
    }
    count[dst] = run;
}

// ---------------- CSR scan ----------------

__global__ __launch_bounds__(1024) void scan_kernel(const int* __restrict__ count,
                                                    int* __restrict__ offsets) {
    const int PER = 20;
    int t = threadIdx.x;
    int base = t * PER;
    int local[PER];
    int sum = 0;
#pragma unroll
    for (int i = 0; i < PER; i++) {
        int idx = base + i;
        int v = (idx < N_NODES) ? count[idx] : 0;
        local[i] = sum;
        sum += v;
    }
    int lane = t & 63, wave = t >> 6;
    int s = sum;
#pragma unroll
    for (int off = 1; off < 64; off <<= 1) {
        int x = __shfl_up(s, off);
        if (lane >= off) s += x;
    }
    __shared__ int wsum[16];
    __shared__ int wpre[16];
    if (lane == 63) wsum[wave] = s;
    __syncthreads();
    if (t == 0) {
        int acc = 0;
        for (int w = 0; w < 16; w++) { wpre[w] = acc; acc += wsum[w]; }
        offsets[N_NODES] = acc;  // == ET
    }
    __syncthreads();
    int thread_excl = wpre[wave] + (s - sum);
#pragma unroll
    for (int i = 0; i < PER; i++) {
        int idx = base + i;
        if (idx < N_NODES) offsets[idx] = thread_excl + local[i];
    }
}

// ---------------- dual GEMM tile (device body, 16 cols/wave) ----------------

template <int K>
__device__ __forceinline__ void dual_gemm_tile(
        const unsigned short* __restrict__ A,
        const unsigned short* __restrict__ Wtl,
        const unsigned short* __restrict__ Wtr,
        const float* __restrict__ bl, const float* __restrict__ br,
        unsigned short* __restrict__ Yl, unsigned short* __restrict__ Yr,
        int M, int NOUT, int bx, int by) {
    const int NK = K / 32;
    int wave = threadIdx.x >> 6;
    int lane = threadIdx.x & 63;
    int row0 = bx * 64;
    int col0 = (by * 4 + wave) * 16;
    int rsub = lane & 15;
    int koff = (lane >> 4) * 8;

    const unsigned short* ap  = A   + (size_t)(row0 + rsub) * K + koff;
    const unsigned short* bpl = Wtl + (size_t)(col0 + rsub) * K + koff;
    const unsigned short* bpr = Wtr + (size_t)(col0 + rsub) * K + koff;

    bf16x8 bfl[NK], bfr[NK];
#pragma unroll
    for (int kb = 0; kb < NK; kb++) {
        bfl[kb] = *(const bf16x8*)(bpl + kb * 32);
        bfr[kb] = *(const bf16x8*)(bpr + kb * 32);
    }

    f32x4 l0 = {0.f, 0.f, 0.f, 0.f};
    f32x4 l1 = l0, l2 = l0, l3 = l0, r0 = l0, r1 = l0, r2 = l0, r3 = l0;

#pragma unroll
    for (int kb = 0; kb < NK; kb++) {
        int off = kb * 32;
        bf16x8 a0 = *(const bf16x8*)(ap + off);
        bf16x8 a1 = *(const bf16x8*)(ap + 16 * K + off);
        bf16x8 a2 = *(const bf16x8*)(ap + 32 * K + off);
        bf16x8 a3 = *(const bf16x8*)(ap + 48 * K + off);
        l0 = __builtin_amdgcn_mfma_f32_16x16x32_bf16(a0, bfl[kb], l0, 0, 0, 0);
        r0 = __builtin_amdgcn_mfma_f32_16x16x32_bf16(a0, bfr[kb], r0, 0, 0, 0);
        l1 = __builtin_amdgcn_mfma_f32_16x16x32_bf16(a1, bfl[kb], l1, 0, 0, 0);
        r1 = __builtin_amdgcn_mfma_f32_16x16x32_bf16(a1, bfr[kb], r1, 0, 0, 0);
        l2 = __builtin_amdgcn_mfma_f32_16x16x32_bf16(a2, bfl[kb], l2, 0, 0, 0);
        r2 = __builtin_amdgcn_mfma_f32_16x16x32_bf16(a2, bfr[kb], r2, 0, 0, 0);
        l3 = __builtin_amdgcn_mfma_f32_16x16x32_bf16(a3, bfl[kb], l3, 0, 0, 0);
        r3 = __builtin_amdgcn_mfma_f32_16x16x32_bf16(a3, bfr[kb], r3, 0, 0, 0);
    }

    int colg = col0 + rsub;
    float bvl = bl[colg];
    float bvr = br[colg];
    int rbase = row0 + (lane >> 4) * 4;
#pragma unroll
    for (int t = 0; t < 4; t++) {
        f32x4 al = (t == 0) ? l0 : (t == 1) ? l1 : (t == 2) ? l2 : l3;
        f32x4 ar = (t == 0) ? r0 : (t == 1) ? r1 : (t == 2) ? r2 : r3;
#pragma unroll
        for (int r = 0; r < 4; r++) {
            int row = rbase + t * 16 + r;
            if (row < M) {
                Yl[(size_t)row * NOUT + colg] = f2b(al[r] + bvl);
                Yr[(size_t)row * NOUT + colg] = f2b(ar[r] + bvr);
            }
        }
    }
}

// ---------------- merged: gemm1 (layer-1 dual GEMM) + edge scatter ----------

__global__ __launch_bounds__(256) void gemm1_scatter_kernel(
        const unsigned short* __restrict__ A,
        const unsigned short* __restrict__ Wtl,
        const unsigned short* __restrict__ Wtr,
        const float* __restrict__ bl, const float* __restrict__ br,
        unsigned short* __restrict__ Yl, unsigned short* __restrict__ Yr,
        const int* __restrict__ edge_src, const int* __restrict__ edge_dst,
        const int* __restrict__ rank, const int* __restrict__ offsets,
        const int* __restrict__ cb, int* __restrict__ sorted_src) {
    int bid = blockIdx.x;
    if (bid < G1_BLOCKS) {
        dual_gemm_tile<IN_CH>(A, Wtl, Wtr, bl, br, Yl, Yr,
                              N_NODES, D1, bid % G1X, bid / G1X);
    } else {
        int e = (bid - G1_BLOCKS) * 256 + threadIdx.x;
        if (e >= ET) return;
        int dst = (e < E_EDGES) ? edge_dst[e] : (e - E_EDGES);
        int src = (e < E_EDGES) ? edge_src[e] : (e - E_EDGES);
        int rep = e / CHUNK;
        sorted_src[offsets[dst] + cb[(size_t)rep * N_NODES + dst] + rank[e]] = src;
    }
}

// ---------------- gemm2: 32 cols/wave (16 MFMA per 4 A-loads) ---------------

template <int K>
__global__ __launch_bounds__(256) void dual_gemm_w32_kernel(
        const unsigned short* __restrict__ A,
        const unsigned short* __restrict__ Wtl,
        const unsigned short* __restrict__ Wtr,
        const float* __restrict__ bl, const float* __restrict__ br,
        unsigned short* __restrict__ Yl, unsigned short* __restrict__ Yr,
        int M, int NOUT) {
    const int NK = K / 32;
    int wave = threadIdx.x >> 6;
    int lane = threadIdx.x & 63;
    int row0 = blockIdx.x * 64;
    int col0 = blockIdx.y * 128 + wave * 32;
    int rsub = lane & 15;
    int koff = (lane >> 4) * 8;

    const unsigned short* ap = A + (size_t)(row0 + rsub) * K + koff;

    bf16x8 bfl[2][NK], bfr[2][NK];
#pragma unroll
    for (int c = 0; c < 2; c++) {
        const unsigned short* bpl = Wtl + (size_t)(col0 + c * 16 + rsub) * K + koff;
        const unsigned short* bpr = Wtr + (size_t)(col0 + c * 16 + rsub) * K + koff;
#pragma unroll
        for (int kb = 0; kb < NK; kb++) {
            bfl[c][kb] = *(const bf16x8*)(bpl + kb * 32);
            bfr[c][kb] = *(const bf16x8*)(bpr + kb * 32);
        }
    }

    f32x4 accl[2][4], accr[2][4];
#pragma unroll
    for (int c = 0; c < 2; c++)
#pragma unroll
        for (int t = 0; t < 4; t++) {
            accl[c][t] = (f32x4){0.f, 0.f, 0.f, 0.f};
            accr[c][t] = (f32x4){0.f, 0.f, 0.f, 0.f};
        }

#pragma unroll
    for (int kb = 0; kb < NK; kb++) {
        int off = kb * 32;
        bf16x8 a[4];
        a[0] = *(const bf16x8*)(ap + off);
        a[1] = *(const bf16x8*)(ap + 16 * K + off);
        a[2] = *(const bf16x8*)(ap + 32 * K + off);
        a[3] = *(const bf16x8*)(ap + 48 * K + off);
#pragma unroll
        for (int t = 0; t < 4; t++) {
#pragma unroll
            for (int c = 0; c < 2; c++) {
                accl[c][t] = __builtin_amdgcn_mfma_f32_16x16x32_bf16(
                    a[t], bfl[c][kb], accl[c][t], 0, 0, 0);
                accr[c][t] = __builtin_amdgcn_mfma_f32_16x16x32_bf16(
                    a[t], bfr[c][kb], accr[c][t], 0, 0, 0);
            }
        }
    }

    int rbase = row0 + (lane >> 4) * 4;
#pragma unroll
    for (int c = 0; c < 2; c++) {
        int colg = col0 + c * 16 + rsub;
        float bvl = bl[colg];
        float bvr = br[colg];
#pragma unroll
        for (int t = 0; t < 4; t++) {
#pragma unroll
            for (int r = 0; r < 4; r++) {
                int row = rbase + t * 16 + r;
                if (row < M) {
                    Yl[(size_t)row * NOUT + colg] = f2b(accl[c][t][r] + bvl);
                    Yr[(size_t)row * NOUT + colg] = f2b(accr[c][t][r] + bvr);
                }
            }
        }
    }
}

// ---------------- layer 1 aggregation (quarter-wave per edge, prefetch-2) ---

__global__ __launch_bounds__(256) void aggregate1_kernel(
        const unsigned short* __restrict__ xl1, const unsigned short* __restrict__ xr1,
        const float* __restrict__ att1, const float* __restrict__ bias1,
        const int* __restrict__ offsets, const int* __restrict__ sorted_src,
        unsigned short* __restrict__ x1) {
    int wave = threadIdx.x >> 6;
    int lane = threadIdx.x & 63;
    int q = lane >> 4;                 // quarter 0..3
    int ql = lane & 15;
    int dst = blockIdx.x * 4 + wave;
    if (dst >= M_PAD) return;
    int c0 = ql * 8;
    if (dst >= N_NODES) {              // zero pad rows for the next GEMM
        if (q == 0) {
            uint4 z; z.x = z.y = z.z = z.w = 0;
            *(uint4*)(x1 + (size_t)dst * D1 + c0) = z;
        }
        return;
    }

    uint4 xu = *(const uint4*)(xr1 + (size_t)dst * D1 + c0);
    f32x2 xr[4] = {up2(xu.x), up2(xu.y), up2(xu.z), up2(xu.w)};
    float4 aa0 = *(const float4*)(att1 + c0);
    float4 aa1 = *(const float4*)(att1 + c0 + 4);
    f32x2 att[4];
    att[0].x = aa0.x * LOG2E; att[0].y = aa0.y * LOG2E;
    att[1].x = aa0.z * LOG2E; att[1].y = aa0.w * LOG2E;
    att[2].x = aa1.x * LOG2E; att[2].y = aa1.y * LOG2E;
    att[3].x = aa1.z * LOG2E; att[3].y = aa1.w * LOG2E;

    int beg = offsets[dst], end = offsets[dst + 1];
    const unsigned short* base = xl1 + c0;

    float l = 0.f;
    f32x2 acc[4] = {{0.f,0.f},{0.f,0.f},{0.f,0.f},{0.f,0.f}};

    int i = beg;
    int s0 = sorted_src[min(i + q, end - 1)];
    uint4 g0 = *(const uint4*)(base + (size_t)s0 * D1);
    bool more1 = (i + 4) < end;
    uint4 g1;
    if (more1) {
        int s1 = sorted_src[min(i + 4 + q, end - 1)];
        g1 = *(const uint4*)(base + (size_t)s1 * D1);
    }
    while (true) {
        bool more2 = (i + 8) < end;
        uint4 g2;
        if (more2) {
            int s2 = sorted_src[min(i + 8 + q, end - 1)];
            g2 = *(const uint4*)(base + (size_t)s2 * D1);
        }
        bool act = (i + q) < end;
        f32x2 v0 = up2(g0.x), v1 = up2(g0.y), v2 = up2(g0.z), v3 = up2(g0.w);
        f32x2 p2 = att[0] * lrelu2(v0 + xr[0]);
        p2 += att[1] * lrelu2(v1 + xr[1]);
        p2 += att[2] * lrelu2(v2 + xr[2]);
        p2 += att[3] * lrelu2(v3 + xr[3]);
        float p = p2.x + p2.y;
        p += __shfl_xor(p, 1);          // head reduce (2 lanes/head)
        float w = act ? EXP2F(p) : 0.f;
        l += w;
        acc[0] += w * v0; acc[1] += w * v1; acc[2] += w * v2; acc[3] += w * v3;
        if (!more1) break;
        i += 4;
        g0 = g1; g1 = g2; more1 = more2;
    }
    // merge quarters
    l += __shfl_xor(l, 16);
    l += __shfl_xor(l, 32);
#pragma unroll
    for (int j = 0; j < 4; j++) {
        f32x2 t;
        t.x = __shfl_xor(acc[j].x, 16); t.y = __shfl_xor(acc[j].y, 16);
        acc[j] += t;
        t.x = __shfl_xor(acc[j].x, 32); t.y = __shfl_xor(acc[j].y, 32);
        acc[j] += t;
    }
    if (q == 0) {
        float inv = 1.f / l;
        float4 bb0 = *(const float4*)(bias1 + c0);
        float4 bb1 = *(const float4*)(bias1 + c0 + 4);
        unsigned short o[8];
        o[0] = f2b(fmaxf(acc[0].x * inv + bb0.x, 0.f));
        o[1] = f2b(fmaxf(acc[0].y * inv + bb0.y, 0.f));
        o[2] = f2b(fmaxf(acc[1].x * inv + bb0.z, 0.f));
        o[3] = f2b(fmaxf(acc[1].y * inv + bb0.w, 0.f));
        o[4] = f2b(fmaxf(acc[2].x * inv + bb1.x, 0.f));
        o[5] = f2b(fmaxf(acc[2].y * inv + bb1.y, 0.f));
        o[6] = f2b(fmaxf(acc[3].x * inv + bb1.z, 0.f));
        o[7] = f2b(fmaxf(acc[3].y * inv + bb1.w, 0.f));
        uint4 ov;
        ov.x = (unsigned int)o[0] | ((unsigned int)o[1] << 16);
        ov.y = (unsigned int)o[2] | ((unsigned int)o[3] << 16);
        ov.z = (unsigned int)o[4] | ((unsigned int)o[5] << 16);
        ov.w = (unsigned int)o[6] | ((unsigned int)o[7] << 16);
        *(uint4*)(x1 + (size_t)dst * D1 + c0) = ov;
    }
}

// ------- fused layer-2 aggregation + classifier: one block per pair ---------
// Waves {0,1} aggregate row a1, waves {2,3} row a2 (half-wave per edge, 4
// edge-slots in flight per dst). Rows land in LDS; classifier dot follows.

__global__ __launch_bounds__(256) void agg2_classifier_kernel(
        const unsigned short* __restrict__ xl2, const unsigned short* __restrict__ xr2,
        const float* __restrict__ att2, const float* __restrict__ bias2,
        const int* __restrict__ offsets, const int* __restrict__ sorted_src,
        const float* __restrict__ vanilla_x,
        const int* __restrict__ a1_raw, const int* __restrict__ a2_raw,
        const float* __restrict__ Wc, const float* __restrict__ bc,
        float* __restrict__ out) {
    __shared__ float x2row[2][D2];     // 2 KB
    __shared__ float mrg[2][32][9];    // 2.25 KB
    __shared__ float part[4];
    __shared__ int stride_s;
    int t = threadIdx.x;
    if (t == 0) {
        bool i64 = true;
        for (int i = 1; i < 63; i += 2) i64 = i64 && (a1_raw[i] == 0);
        stride_s = i64 ? 2 : 1;
    }
    __syncthreads();
    int stride = stride_s;
    int b = blockIdx.x;
    int a1 = a1_raw[(long)b * stride];
    int a2 = a2_raw[(long)b * stride];

    int wave = t >> 6;                 // 0..3
    int d = wave >> 1;                 // dst slot 0/1
    int ww = wave & 1;                 // wave within pair
    int lane = t & 63;
    int half = lane >> 5;
    int hl = lane & 31;
    int c0 = hl * 8;
    int dst = d ? a2 : a1;

    float xr[8], att[8];
    unpack8(*(const uint4*)(xr2 + (size_t)dst * D2 + c0), xr);
#pragma unroll
    for (int j = 0; j < 8; j++) att[j] = att2[c0 + j] * LOG2E;
    int beg = offsets[dst], end = offsets[dst + 1];

    float l = 0.f;
    float acc[8];
#pragma unroll
    for (int j = 0; j < 8; j++) acc[j] = 0.f;

    int sub = 2 * ww + half;           // edge slot 0..3
    for (int i0 = beg; i0 < end; i0 += 4) {
        int idx = i0 + sub;
        bool act = idx < end;
        int s = sorted_src[min(idx, end - 1)];
        float v[8];
        unpack8(*(const uint4*)(xl2 + (size_t)s * D2 + c0), v);
        float p = 0.f;
#pragma unroll
        for (int j = 0; j < 8; j++) p = fmaf(att[j], lrelu(v[j] + xr[j]), p);
        p += __shfl_xor(p, 1);
        p += __shfl_xor(p, 2);
        p += __shfl_xor(p, 4);
        p += __shfl_xor(p, 8);
        p += __shfl_xor(p, 16);
        float w = act ? EXP2F(p) : 0.f;
        l += w;
#pragma unroll
        for (int j = 0; j < 8; j++) acc[j] += w * v[j];
    }
    // merge halves within wave
    l += __shfl_xor(l, 32);
#pragma unroll
    for (int j = 0; j < 8; j++) acc[j] += __shfl_xor(acc[j], 32);
    // merge across the wave pair via LDS
    if (ww == 1 && half == 0) {
        mrg[d][hl][0] = l;
#pragma unroll
        for (int j = 0; j < 8; j++) mrg[d][hl][1 + j] = acc[j];
    }
    __syncthreads();
    if (ww == 0 && half == 0) {
        l += mrg[d][hl][0];
#pragma unroll
        for (int j = 0; j < 8; j++) acc[j] += mrg[d][hl][1 + j];
        float inv = 1.f / l;
#pragma unroll
        for (int j = 0; j < 8; j++)
            x2row[d][c0 + j] = acc[j] * inv + bias2[c0 + j];
    }
    __syncthreads();

    // classifier dot: thread t owns channel t of each of the 4 segments
    float s = vanilla_x[(size_t)a1 * IN_CH + t] * Wc[t]
            + vanilla_x[(size_t)a2 * IN_CH + t] * Wc[IN_CH + t]
            + x2row[0][t] * Wc[2 * IN_CH + t]
            + x2row[1][t] * Wc[3 * IN_CH + t];
    s += __shfl_xor(s, 1);
    s += __shfl_xor(s, 2);
    s += __shfl_xor(s, 4);
    s += __shfl_xor(s, 8);
    s += __shfl_xor(s, 16);
    s += __shfl_xor(s, 32);
    if (lane == 0) part[wave] = s;
    __syncthreads();
    if (t == 0) out[b] = part[0] + part[1] + part[2] + part[3] + bc[0];
}

// ---------------- launch ----------------

extern "C" void kernel_launch(void* const* d_in, const int* in_sizes, int n_in,
                              void* d_out, int out_size, void* d_ws, size_t ws_size,
                              hipStream_t stream) {
    const float* gnn_x     = (const float*)d_in[0];
    const float* vanilla_x = (const float*)d_in[1];
    const int*   edge_src  = (const int*)d_in[2];
    const int*   edge_dst  = (const int*)d_in[3];
    const int*   a1_idx    = (const int*)d_in[4];
    const int*   a2_idx    = (const int*)d_in[5];
    const float* Wl1   = (const float*)d_in[6];
    const float* bl1   = (const float*)d_in[7];
    const float* Wr1   = (const float*)d_in[8];
    const float* br1   = (const float*)d_in[9];
    const float* att1  = (const float*)d_in[10];
    const float* bias1 = (const float*)d_in[11];
    const float* Wl2   = (const float*)d_in[12];
    const float* bl2   = (const float*)d_in[13];
    const float* Wr2   = (const float*)d_in[14];
    const float* br2   = (const float*)d_in[15];
    const float* att2  = (const float*)d_in[16];
    const float* bias2 = (const float*)d_in[17];
    const float* Wc    = (const float*)d_in[18];
    const float* bc    = (const float*)d_in[19];
    float* out = (float*)d_out;

    // workspace layout
    char* p = (char*)d_ws;
    unsigned short* xb   = (unsigned short*)p; p += (size_t)M_PAD * IN_CH * 2;
    unsigned short* x1b  = (unsigned short*)p; p += (size_t)M_PAD * D1 * 2;
    unsigned short* xl1b = (unsigned short*)p; p += (size_t)N_NODES * D1 * 2;
    unsigned short* xr1b = (unsigned short*)p; p += (size_t)N_NODES * D1 * 2;
    unsigned short* xl2b = (unsigned short*)p; p += (size_t)N_NODES * D2 * 2;
    unsigned short* xr2b = (unsigned short*)p; p += (size_t)N_NODES * D2 * 2;
    unsigned short* wt1l = (unsigned short*)p; p += (size_t)D1 * IN_CH * 2;
    unsigned short* wt1r = (unsigned short*)p; p += (size_t)D1 * IN_CH * 2;
    unsigned short* wt2l = (unsigned short*)p; p += (size_t)D2 * D1 * 2;
    unsigned short* wt2r = (unsigned short*)p; p += (size_t)D2 * D1 * 2;
    int* count      = (int*)p; p += (size_t)N_NODES * 4;
    int* offsets    = (int*)p; p += (size_t)(N_NODES + 4) * 4;
    int* rank       = (int*)p; p += (size_t)ET * 4;
    int* sorted_src = (int*)p; p += (size_t)ET * 4;
    // cb aliases xl2b: alive prep..scatter; xl2b written by gemm2 afterwards.
    int* cb = (int*)xl2b;

    prep_kernel<<<NB_HIST + WT_BLOCKS + XCONV_BLOCKS, 256, 0, stream>>>(
        gnn_x, Wl1, Wr1, Wl2, Wr2, edge_dst,
        xb, wt1l, wt1r, wt2l, wt2r, cb, rank);
    repprefix_kernel<<<(N_NODES + 255) / 256, 256, 0, stream>>>(cb, count);
    scan_kernel<<<1, 1024, 0, stream>>>(count, offsets);

    // layer-1 dual GEMM + edge scatter (independent; one dispatch)
    gemm1_scatter_kernel<<<G1_BLOCKS + SCAT_BLOCKS, 256, 0, stream>>>(
        xb, wt1l, wt1r, bl1, br1, xl1b, xr1b,
        edge_src, edge_dst, rank, offsets, cb, sorted_src);

    aggregate1_kernel<<<M_PAD / 4, 256, 0, stream>>>(
        xl1b, xr1b, att1, bias1, offsets, sorted_src, x1b);

    // layer 2: 32-col-per-wave dual GEMM
    dim3 g2(M_PAD / 64, D2 / 128);   // (313, 2)
    dual_gemm_w32_kernel<D1><<<g2, 256, 0, stream>>>(
        x1b, wt2l, wt2r, bl2, br2, xl2b, xr2b, N_NODES, D2);

    // fused layer-2 aggregation + classifier (one block per pair)
    agg2_classifier_kernel<<<BPAIRS, 256, 0, stream>>>(
        xl2b, xr2b, att2, bias2, offsets, sorted_src,
        vanilla_x, a1_idx, a2_idx, Wc, bc, out);
}

// Round 14
// 256.873 us; speedup vs baseline: 1.0616x; 1.0209x over previous
//
#include <hip/hip_runtime.h>
#include <math.h>

#define N_NODES 20000
#define M_PAD   20032            // 64-row padded for MFMA row tiles
#define E_EDGES 640000
#define ET (E_EDGES + N_NODES)   // edges + self loops
#define IN_CH 256
#define D1 128                   // H1*C1 = 8*16
#define D2 256                   // H2*C2 = 1*256
#define BPAIRS 4096
#define NEG 0.2f
#define LOG2E 1.4426950408889634f

#define NB_HIST   128
#define CHUNK     ((ET + NB_HIST - 1) / NB_HIST)   // 5157
#define HALF_BINS 10000

#define WT_BLOCKS    32                           // 4 matrices x 8 64x64 tiles
#define XCONV_BLOCKS (M_PAD * IN_CH / 4 / 4 / 256) // 1252 (ILP-4)

#define G1X (M_PAD / 64)          // 313
#define G1Y (D1 / 64)             // 2
#define G1_BLOCKS (G1X * G1Y)     // 626
#define SCAT_BLOCKS ((ET + 255) / 256)  // 2579

#if __has_builtin(__builtin_amdgcn_exp2f)
#define EXP2F(x) __builtin_amdgcn_exp2f(x)
#else
#define EXP2F(x) exp2f(x)
#endif

typedef __bf16 bf16x8 __attribute__((ext_vector_type(8)));
typedef float  f32x4  __attribute__((ext_vector_type(4)));
typedef float  f32x2  __attribute__((ext_vector_type(2)));
typedef unsigned short u16x4 __attribute__((ext_vector_type(4)));

__device__ __forceinline__ unsigned short f2b(float f) {
    unsigned int u = __float_as_uint(f);
    unsigned int r = u + 0x7FFFu + ((u >> 16) & 1u);   // RNE
    return (unsigned short)(r >> 16);
}
// f32 -> fp8 e4m3 (OCP), RNE via HW cvt
__device__ __forceinline__ unsigned char f2f8(float f) {
    return (unsigned char)(__builtin_amdgcn_cvt_pk_fp8_f32(f, f, 0, false) & 0xFF);
}
// 2 fp8 (bytes 0..1 if !HI, bytes 2..3 if HI) -> 2 f32; HI must be constexpr
template <bool HI>
__device__ __forceinline__ f32x2 f8up2(unsigned int u) {
    return __builtin_amdgcn_cvt_pk_f32_fp8((int)u, HI);
}
__device__ __forceinline__ f32x2 up2(unsigned int u) {
    f32x2 r;
    r.x = __uint_as_float(u << 16);
    r.y = __uint_as_float(u & 0xFFFF0000u);
    return r;
}
__device__ __forceinline__ f32x2 lrelu2(f32x2 s) {
    return __builtin_elementwise_max(s, s * NEG);
}
__device__ __forceinline__ float lrelu(float s) { return fmaxf(s, NEG * s); }

__device__ __forceinline__ void unpack8(uint4 u, float* v) {
    v[0] = __uint_as_float(u.x << 16); v[1] = __uint_as_float(u.x & 0xFFFF0000u);
    v[2] = __uint_as_float(u.y << 16); v[3] = __uint_as_float(u.y & 0xFFFF0000u);
    v[4] = __uint_as_float(u.z << 16); v[5] = __uint_as_float(u.z & 0xFFFF0000u);
    v[6] = __uint_as_float(u.w << 16); v[7] = __uint_as_float(u.w & 0xFFFF0000u);
}
__device__ __forceinline__ void unpack8_f8(uint2 u, float* v) {
    f32x2 a = f8up2<false>(u.x), b = f8up2<true>(u.x);
    f32x2 c = f8up2<false>(u.y), d = f8up2<true>(u.y);
    v[0] = a.x; v[1] = a.y; v[2] = b.x; v[3] = b.y;
    v[4] = c.x; v[5] = c.y; v[6] = d.x; v[7] = d.y;
}

// ------- fused prep: LDS histogram + LDS-tiled W^T + x conversion -----------

__global__ __launch_bounds__(256) void prep_kernel(
        const float* __restrict__ gnn_x,
        const float* __restrict__ Wl1, const float* __restrict__ Wr1,
        const float* __restrict__ Wl2, const float* __restrict__ Wr2,
        const int* __restrict__ edge_dst,
        unsigned short* __restrict__ xb,
        unsigned short* __restrict__ wt1l, unsigned short* __restrict__ wt1r,
        unsigned short* __restrict__ wt2l, unsigned short* __restrict__ wt2r,
        int* __restrict__ cb,              // [NB_HIST][N_NODES] block counts
        int* __restrict__ rank) {
    __shared__ int lc[HALF_BINS];          // 40 KB (reused as transpose tile)
    int bid = blockIdx.x;
    if (bid < NB_HIST) {
        // per-chunk LDS histogram; rank = order within (chunk, dst)
        int ebeg = bid * CHUNK;
        int eend = min(ebeg + CHUNK, ET);
#pragma unroll 1
        for (int half = 0; half < 2; half++) {
            int lo = half * HALF_BINS;
            for (int i = threadIdx.x; i < HALF_BINS; i += 256) lc[i] = 0;
            __syncthreads();
            for (int e = ebeg + threadIdx.x; e < eend; e += 256) {
                int dst = (e < E_EDGES) ? edge_dst[e] : (e - E_EDGES);
                int d = dst - lo;
                if (0 <= d && d < HALF_BINS) rank[e] = atomicAdd(&lc[d], 1);
            }
            __syncthreads();
            for (int i = threadIdx.x; i < HALF_BINS; i += 256)
                cb[(size_t)bid * N_NODES + lo + i] = lc[i];
            __syncthreads();
        }
    } else if (bid < NB_HIST + WT_BLOCKS) {
        // W [K x N] -> Wt [N x K] via 64x64 LDS tile; coalesced both sides
        unsigned short* tile = (unsigned short*)lc;      // 64 x 65 bf16
        int t = bid - NB_HIST;                           // 0..31
        int m = t >> 3;                                  // matrix 0..3
        int tt = t & 7;                                  // tile in matrix
        const float* W;
        unsigned short* Wt;
        int K, N;
        if (m == 0)      { W = Wl1; Wt = wt1l; K = IN_CH; N = D1; }
        else if (m == 1) { W = Wr1; Wt = wt1r; K = IN_CH; N = D1; }
        else if (m == 2) { W = Wl2; Wt = wt2l; K = D1; N = D2; }
        else             { W = Wr2; Wt = wt2r; K = D1; N = D2; }
        int ntn = N >> 6;                                // n-tiles per matrix
        int k0 = (tt / ntn) << 6;
        int n0 = (tt % ntn) << 6;
        int c = threadIdx.x & 63;
        int rr = threadIdx.x >> 6;                       // 0..3
#pragma unroll
        for (int ch = 0; ch < 16; ch++) {
            int row = rr * 16 + ch;
            tile[row * 65 + c] = f2b(W[(size_t)(k0 + row) * N + n0 + c]);
        }
        __syncthreads();
#pragma unroll
        for (int ch = 0; ch < 16; ch++) {
            int n = rr * 16 + ch;
            Wt[(size_t)(n0 + n) * K + k0 + c] = tile[c * 65 + n];
        }
    } else {
        // x -> bf16 with zero row padding; ILP-4, NT load
        int tid = (bid - NB_HIST - WT_BLOCKS) * 256 + threadIdx.x;
        const int NQ = M_PAD * IN_CH / 4;  // total float4 groups
        int q0 = tid * 4;
#pragma unroll
        for (int j = 0; j < 4; j++) {
            int qi = q0 + j;
            if (qi >= NQ) break;
            int e0 = qi * 4;
            int row = e0 >> 8;             // / IN_CH
            u16x4 o;
            if (row < N_NODES) {
                f32x4 v = __builtin_nontemporal_load((const f32x4*)(gnn_x + e0));
                o.x = f2b(v.x); o.y = f2b(v.y); o.z = f2b(v.z); o.w = f2b(v.w);
            } else {
                o.x = o.y = o.z = o.w = 0;
            }
            *(u16x4*)(xb + e0) = o;
        }
    }
}

// ---- per-dst exclusive prefix over hist blocks; writes total to count ------

__global__ __launch_bounds__(256) void repprefix_kernel(
        int* __restrict__ cb, int* __restrict__ count) {
    int dst = blockIdx.x * 256 + threadIdx.x;
    if (dst >= N_NODES) return;
    int run = 0;
#pragma unroll 4
    for (int r = 0; r < NB_HIST; r++) {
        size_t idx = (size_t)r * N_NODES + dst;
        int c = cb[idx];
        cb[idx] = run;
        run += c;
    }
    count[dst] = run;
}

// ---------------- CSR scan ----------------

__global__ __launch_bounds__(1024) void scan_kernel(const int* __restrict__ count,
                                                    int* __restrict__ offsets) {
    const int PER = 20;
    int t = threadIdx.x;
    int base = t * PER;
    int local[PER];
    int sum = 0;
#pragma unroll
    for (int i = 0; i < PER; i++) {
        int idx = base + i;
        int v = (idx < N_NODES) ? count[idx] : 0;
        local[i] = sum;
        sum += v;
    }
    int lane = t & 63, wave = t >> 6;
    int s = sum;
#pragma unroll
    for (int off = 1; off < 64; off <<= 1) {
        int x = __shfl_up(s, off);
        if (lane >= off) s += x;
    }
    __shared__ int wsum[16];
    __shared__ int wpre[16];
    if (lane == 63) wsum[wave] = s;
    __syncthreads();
    if (t == 0) {
        int acc = 0;
        for (int w = 0; w < 16; w++) { wpre[w] = acc; acc += wsum[w]; }
        offsets[N_NODES] = acc;  // == ET
    }
    __syncthreads();
    int thread_excl = wpre[wave] + (s - sum);
#pragma unroll
    for (int i = 0; i < PER; i++) {
        int idx = base + i;
        if (idx < N_NODES) offsets[idx] = thread_excl + local[i];
    }
}

// -------- dual GEMM tile (device body, 16 cols/wave; Yl fp8, Yr bf16) -------

template <int K>
__device__ __forceinline__ void dual_gemm_tile(
        const unsigned short* __restrict__ A,
        const unsigned short* __restrict__ Wtl,
        const unsigned short* __restrict__ Wtr,
        const float* __restrict__ bl, const float* __restrict__ br,
        unsigned char* __restrict__ Yl, unsigned short* __restrict__ Yr,
        int M, int NOUT, int bx, int by) {
    const int NK = K / 32;
    int wave = threadIdx.x >> 6;
    int lane = threadIdx.x & 63;
    int row0 = bx * 64;
    int col0 = (by * 4 + wave) * 16;
    int rsub = lane & 15;
    int koff = (lane >> 4) * 8;

    const unsigned short* ap  = A   + (size_t)(row0 + rsub) * K + koff;
    const unsigned short* bpl = Wtl + (size_t)(col0 + rsub) * K + koff;
    const unsigned short* bpr = Wtr + (size_t)(col0 + rsub) * K + koff;

    bf16x8 bfl[NK], bfr[NK];
#pragma unroll
    for (int kb = 0; kb < NK; kb++) {
        bfl[kb] = *(const bf16x8*)(bpl + kb * 32);
        bfr[kb] = *(const bf16x8*)(bpr + kb * 32);
    }

    f32x4 l0 = {0.f, 0.f, 0.f, 0.f};
    f32x4 l1 = l0, l2 = l0, l3 = l0, r0 = l0, r1 = l0, r2 = l0, r3 = l0;

#pragma unroll
    for (int kb = 0; kb < NK; kb++) {
        int off = kb * 32;
        bf16x8 a0 = *(const bf16x8*)(ap + off);
        bf16x8 a1 = *(const bf16x8*)(ap + 16 * K + off);
        bf16x8 a2 = *(const bf16x8*)(ap + 32 * K + off);
        bf16x8 a3 = *(const bf16x8*)(ap + 48 * K + off);
        l0 = __builtin_amdgcn_mfma_f32_16x16x32_bf16(a0, bfl[kb], l0, 0, 0, 0);
        r0 = __builtin_amdgcn_mfma_f32_16x16x32_bf16(a0, bfr[kb], r0, 0, 0, 0);
        l1 = __builtin_amdgcn_mfma_f32_16x16x32_bf16(a1, bfl[kb], l1, 0, 0, 0);
        r1 = __builtin_amdgcn_mfma_f32_16x16x32_bf16(a1, bfr[kb], r1, 0, 0, 0);
        l2 = __builtin_amdgcn_mfma_f32_16x16x32_bf16(a2, bfl[kb], l2, 0, 0, 0);
        r2 = __builtin_amdgcn_mfma_f32_16x16x32_bf16(a2, bfr[kb], r2, 0, 0, 0);
        l3 = __builtin_amdgcn_mfma_f32_16x16x32_bf16(a3, bfl[kb], l3, 0, 0, 0);
        r3 = __builtin_amdgcn_mfma_f32_16x16x32_bf16(a3, bfr[kb], r3, 0, 0, 0);
    }

    int colg = col0 + rsub;
    float bvl = bl[colg];
    float bvr = br[colg];
    int rbase = row0 + (lane >> 4) * 4;
#pragma unroll
    for (int t = 0; t < 4; t++) {
        f32x4 al = (t == 0) ? l0 : (t == 1) ? l1 : (t == 2) ? l2 : l3;
        f32x4 ar = (t == 0) ? r0 : (t == 1) ? r1 : (t == 2) ? r2 : r3;
#pragma unroll
        for (int r = 0; r < 4; r++) {
            int row = rbase + t * 16 + r;
            if (row < M) {
                Yl[(size_t)row * NOUT + colg] = f2f8(al[r] + bvl);
                Yr[(size_t)row * NOUT + colg] = f2b(ar[r] + bvr);
            }
        }
    }
}

// ---------------- merged: gemm1 (layer-1 dual GEMM) + edge scatter ----------

__global__ __launch_bounds__(256) void gemm1_scatter_kernel(
        const unsigned short* __restrict__ A,
        const unsigned short* __restrict__ Wtl,
        const unsigned short* __restrict__ Wtr,
        const float* __restrict__ bl, const float* __restrict__ br,
        unsigned char* __restrict__ Yl, unsigned short* __restrict__ Yr,
        const int* __restrict__ edge_src, const int* __restrict__ edge_dst,
        const int* __restrict__ rank, const int* __restrict__ offsets,
        const int* __restrict__ cb, int* __restrict__ sorted_src) {
    int bid = blockIdx.x;
    if (bid < G1_BLOCKS) {
        dual_gemm_tile<IN_CH>(A, Wtl, Wtr, bl, br, Yl, Yr,
                              N_NODES, D1, bid % G1X, bid / G1X);
    } else {
        int e = (bid - G1_BLOCKS) * 256 + threadIdx.x;
        if (e >= ET) return;
        int dst = (e < E_EDGES) ? edge_dst[e] : (e - E_EDGES);
        int src = (e < E_EDGES) ? edge_src[e] : (e - E_EDGES);
        int rep = e / CHUNK;
        sorted_src[offsets[dst] + cb[(size_t)rep * N_NODES + dst] + rank[e]] = src;
    }
}

// -------- gemm2: 32 cols/wave (16 MFMA per 4 A-loads); Yl fp8, Yr bf16 ------

template <int K>
__global__ __launch_bounds__(256) void dual_gemm_w32_kernel(
        const unsigned short* __restrict__ A,
        const unsigned short* __restrict__ Wtl,
        const unsigned short* __restrict__ Wtr,
        const float* __restrict__ bl, const float* __restrict__ br,
        unsigned char* __restrict__ Yl, unsigned short* __restrict__ Yr,
        int M, int NOUT) {
    const int NK = K / 32;
    int wave = threadIdx.x >> 6;
    int lane = threadIdx.x & 63;
    int row0 = blockIdx.x * 64;
    int col0 = blockIdx.y * 128 + wave * 32;
    int rsub = lane & 15;
    int koff = (lane >> 4) * 8;

    const unsigned short* ap = A + (size_t)(row0 + rsub) * K + koff;

    bf16x8 bfl[2][NK], bfr[2][NK];
#pragma unroll
    for (int c = 0; c < 2; c++) {
        const unsigned short* bpl = Wtl + (size_t)(col0 + c * 16 + rsub) * K + koff;
        const unsigned short* bpr = Wtr + (size_t)(col0 + c * 16 + rsub) * K + koff;
#pragma unroll
        for (int kb = 0; kb < NK; kb++) {
            bfl[c][kb] = *(const bf16x8*)(bpl + kb * 32);
            bfr[c][kb] = *(const bf16x8*)(bpr + kb * 32);
        }
    }

    f32x4 accl[2][4], accr[2][4];
#pragma unroll
    for (int c = 0; c < 2; c++)
#pragma unroll
        for (int t = 0; t < 4; t++) {
            accl[c][t] = (f32x4){0.f, 0.f, 0.f, 0.f};
            accr[c][t] = (f32x4){0.f, 0.f, 0.f, 0.f};
        }

#pragma unroll
    for (int kb = 0; kb < NK; kb++) {
        int off = kb * 32;
        bf16x8 a[4];
        a[0] = *(const bf16x8*)(ap + off);
        a[1] = *(const bf16x8*)(ap + 16 * K + off);
        a[2] = *(const bf16x8*)(ap + 32 * K + off);
        a[3] = *(const bf16x8*)(ap + 48 * K + off);
#pragma unroll
        for (int t = 0; t < 4; t++) {
#pragma unroll
            for (int c = 0; c < 2; c++) {
                accl[c][t] = __builtin_amdgcn_mfma_f32_16x16x32_bf16(
                    a[t], bfl[c][kb], accl[c][t], 0, 0, 0);
                accr[c][t] = __builtin_amdgcn_mfma_f32_16x16x32_bf16(
                    a[t], bfr[c][kb], accr[c][t], 0, 0, 0);
            }
        }
    }

    int rbase = row0 + (lane >> 4) * 4;
#pragma unroll
    for (int c = 0; c < 2; c++) {
        int colg = col0 + c * 16 + rsub;
        float bvl = bl[colg];
        float bvr = br[colg];
#pragma unroll
        for (int t = 0; t < 4; t++) {
#pragma unroll
            for (int r = 0; r < 4; r++) {
                int row = rbase + t * 16 + r;
                if (row < M) {
                    Yl[(size_t)row * NOUT + colg] = f2f8(accl[c][t][r] + bvl);
                    Yr[(size_t)row * NOUT + colg] = f2b(accr[c][t][r] + bvr);
                }
            }
        }
    }
}

// -------- layer 1 aggregation (quarter-wave per edge, prefetch-2, fp8) ------

__global__ __launch_bounds__(256) void aggregate1_kernel(
        const unsigned char* __restrict__ xl1, const unsigned short* __restrict__ xr1,
        const float* __restrict__ att1, const float* __restrict__ bias1,
        const int* __restrict__ offsets, const int* __restrict__ sorted_src,
        unsigned short* __restrict__ x1) {
    int wave = threadIdx.x >> 6;
    int lane = threadIdx.x & 63;
    int q = lane >> 4;                 // quarter 0..3
    int ql = lane & 15;
    int dst = blockIdx.x * 4 + wave;
    if (dst >= M_PAD) return;
    int c0 = ql * 8;                   // channel index (8 ch/lane)
    if (dst >= N_NODES) {              // zero pad rows for the next GEMM
        if (q == 0) {
            uint4 z; z.x = z.y = z.z = z.w = 0;
            *(uint4*)(x1 + (size_t)dst * D1 + c0) = z;
        }
        return;
    }

    uint4 xu = *(const uint4*)(xr1 + (size_t)dst * D1 + c0);
    f32x2 xr[4] = {up2(xu.x), up2(xu.y), up2(xu.z), up2(xu.w)};
    float4 aa0 = *(const float4*)(att1 + c0);
    float4 aa1 = *(const float4*)(att1 + c0 + 4);
    f32x2 att[4];
    att[0].x = aa0.x * LOG2E; att[0].y = aa0.y * LOG2E;
    att[1].x = aa0.z * LOG2E; att[1].y = aa0.w * LOG2E;
    att[2].x = aa1.x * LOG2E; att[2].y = aa1.y * LOG2E;
    att[3].x = aa1.z * LOG2E; att[3].y = aa1.w * LOG2E;

    int beg = offsets[dst], end = offsets[dst + 1];
    const unsigned char* base = xl1 + c0;   // fp8: 1 byte/ch, row stride D1 B

    float l = 0.f;
    f32x2 acc[4] = {{0.f,0.f},{0.f,0.f},{0.f,0.f},{0.f,0.f}};

    int i = beg;
    int s0 = sorted_src[min(i + q, end - 1)];
    uint2 g0 = *(const uint2*)(base + (size_t)s0 * D1);
    bool more1 = (i + 4) < end;
    uint2 g1;
    if (more1) {
        int s1 = sorted_src[min(i + 4 + q, end - 1)];
        g1 = *(const uint2*)(base + (size_t)s1 * D1);
    }
    while (true) {
        bool more2 = (i + 8) < end;
        uint2 g2;
        if (more2) {
            int s2 = sorted_src[min(i + 8 + q, end - 1)];
            g2 = *(const uint2*)(base + (size_t)s2 * D1);
        }
        bool act = (i + q) < end;
        f32x2 v0 = f8up2<false>(g0.x), v1 = f8up2<true>(g0.x);
        f32x2 v2 = f8up2<false>(g0.y), v3 = f8up2<true>(g0.y);
        f32x2 p2 = att[0] * lrelu2(v0 + xr[0]);
        p2 += att[1] * lrelu2(v1 + xr[1]);
        p2 += att[2] * lrelu2(v2 + xr[2]);
        p2 += att[3] * lrelu2(v3 + xr[3]);
        float p = p2.x + p2.y;
        p += __shfl_xor(p, 1);          // head reduce (2 lanes/head)
        float w = act ? EXP2F(p) : 0.f;
        l += w;
        acc[0] += w * v0; acc[1] += w * v1; acc[2] += w * v2; acc[3] += w * v3;
        if (!more1) break;
        i += 4;
        g0 = g1; g1 = g2; more1 = more2;
    }
    // merge quarters
    l += __shfl_xor(l, 16);
    l += __shfl_xor(l, 32);
#pragma unroll
    for (int j = 0; j < 4; j++) {
        f32x2 t;
        t.x = __shfl_xor(acc[j].x, 16); t.y = __shfl_xor(acc[j].y, 16);
        acc[j] += t;
        t.x = __shfl_xor(acc[j].x, 32); t.y = __shfl_xor(acc[j].y, 32);
        acc[j] += t;
    }
    if (q == 0) {
        float inv = 1.f / l;
        float4 bb0 = *(const float4*)(bias1 + c0);
        float4 bb1 = *(const float4*)(bias1 + c0 + 4);
        unsigned short o[8];
        o[0] = f2b(fmaxf(acc[0].x * inv + bb0.x, 0.f));
        o[1] = f2b(fmaxf(acc[0].y * inv + bb0.y, 0.f));
        o[2] = f2b(fmaxf(acc[1].x * inv + bb0.z, 0.f));
        o[3] = f2b(fmaxf(acc[1].y * inv + bb0.w, 0.f));
        o[4] = f2b(fmaxf(acc[2].x * inv + bb1.x, 0.f));
        o[5] = f2b(fmaxf(acc[2].y * inv + bb1.y, 0.f));
        o[6] = f2b(fmaxf(acc[3].x * inv + bb1.z, 0.f));
        o[7] = f2b(fmaxf(acc[3].y * inv + bb1.w, 0.f));
        uint4 ov;
        ov.x = (unsigned int)o[0] | ((unsigned int)o[1] << 16);
        ov.y = (unsigned int)o[2] | ((unsigned int)o[3] << 16);
        ov.z = (unsigned int)o[4] | ((unsigned int)o[5] << 16);
        ov.w = (unsigned int)o[6] | ((unsigned int)o[7] << 16);
        *(uint4*)(x1 + (size_t)dst * D1 + c0) = ov;
    }
}

// ------- fused layer-2 aggregation + classifier: one block per pair ---------
// Waves {0,1} aggregate row a1, waves {2,3} row a2 (half-wave per edge, 4
// edge-slots in flight per dst). xl2 gathered as fp8. Classifier dot follows.

__global__ __launch_bounds__(256) void agg2_classifier_kernel(
        const unsigned char* __restrict__ xl2, const unsigned short* __restrict__ xr2,
        const float* __restrict__ att2, const float* __restrict__ bias2,
        const int* __restrict__ offsets, const int* __restrict__ sorted_src,
        const float* __restrict__ vanilla_x,
        const int* __restrict__ a1_raw, const int* __restrict__ a2_raw,
        const float* __restrict__ Wc, const float* __restrict__ bc,
        float* __restrict__ out) {
    __shared__ float x2row[2][D2];     // 2 KB
    __shared__ float mrg[2][32][9];    // 2.25 KB
    __shared__ float part[4];
    __shared__ int stride_s;
    int t = threadIdx.x;
    if (t == 0) {
        bool i64 = true;
        for (int i = 1; i < 63; i += 2) i64 = i64 && (a1_raw[i] == 0);
        stride_s = i64 ? 2 : 1;
    }
    __syncthreads();
    int stride = stride_s;
    int b = blockIdx.x;
    int a1 = a1_raw[(long)b * stride];
    int a2 = a2_raw[(long)b * stride];

    int wave = t >> 6;                 // 0..3
    int d = wave >> 1;                 // dst slot 0/1
    int ww = wave & 1;                 // wave within pair
    int lane = t & 63;
    int half = lane >> 5;
    int hl = lane & 31;
    int c0 = hl * 8;
    int dst = d ? a2 : a1;

    float xr[8], att[8];
    unpack8(*(const uint4*)(xr2 + (size_t)dst * D2 + c0), xr);
#pragma unroll
    for (int j = 0; j < 8; j++) att[j] = att2[c0 + j] * LOG2E;
    int beg = offsets[dst], end = offsets[dst + 1];

    float l = 0.f;
    float acc[8];
#pragma unroll
    for (int j = 0; j < 8; j++) acc[j] = 0.f;

    int sub = 2 * ww + half;           // edge slot 0..3
    for (int i0 = beg; i0 < end; i0 += 4) {
        int idx = i0 + sub;
        bool act = idx < end;
        int s = sorted_src[min(idx, end - 1)];
        float v[8];
        unpack8_f8(*(const uint2*)(xl2 + (size_t)s * D2 + c0), v);
        float p = 0.f;
#pragma unroll
        for (int j = 0; j < 8; j++) p = fmaf(att[j], lrelu(v[j] + xr[j]), p);
        p += __shfl_xor(p, 1);
        p += __shfl_xor(p, 2);
        p += __shfl_xor(p, 4);
        p += __shfl_xor(p, 8);
        p += __shfl_xor(p, 16);
        float w = act ? EXP2F(p) : 0.f;
        l += w;
#pragma unroll
        for (int j = 0; j < 8; j++) acc[j] += w * v[j];
    }
    // merge halves within wave
    l += __shfl_xor(l, 32);
#pragma unroll
    for (int j = 0; j < 8; j++) acc[j] += __shfl_xor(acc[j], 32);
    // merge across the wave pair via LDS
    if (ww == 1 && half == 0) {
        mrg[d][hl][0] = l;
#pragma unroll
        for (int j = 0; j < 8; j++) mrg[d][hl][1 + j] = acc[j];
    }
    __syncthreads();
    if (ww == 0 && half == 0) {
        l += mrg[d][hl][0];
#pragma unroll
        for (int j = 0; j < 8; j++) acc[j] += mrg[d][hl][1 + j];
        float inv = 1.f / l;
#pragma unroll
        for (int j = 0; j < 8; j++)
            x2row[d][c0 + j] = acc[j] * inv + bias2[c0 + j];
    }
    __syncthreads();

    // classifier dot: thread t owns channel t of each of the 4 segments
    float s = vanilla_x[(size_t)a1 * IN_CH + t] * Wc[t]
            + vanilla_x[(size_t)a2 * IN_CH + t] * Wc[IN_CH + t]
            + x2row[0][t] * Wc[2 * IN_CH + t]
            + x2row[1][t] * Wc[3 * IN_CH + t];
    s += __shfl_xor(s, 1);
    s += __shfl_xor(s, 2);
    s += __shfl_xor(s, 4);
    s += __shfl_xor(s, 8);
    s += __shfl_xor(s, 16);
    s += __shfl_xor(s, 32);
    if (lane == 0) part[wave] = s;
    __syncthreads();
    if (t == 0) out[b] = part[0] + part[1] + part[2] + part[3] + bc[0];
}

// ---------------- launch ----------------

extern "C" void kernel_launch(void* const* d_in, const int* in_sizes, int n_in,
                              void* d_out, int out_size, void* d_ws, size_t ws_size,
                              hipStream_t stream) {
    const float* gnn_x     = (const float*)d_in[0];
    const float* vanilla_x = (const float*)d_in[1];
    const int*   edge_src  = (const int*)d_in[2];
    const int*   edge_dst  = (const int*)d_in[3];
    const int*   a1_idx    = (const int*)d_in[4];
    const int*   a2_idx    = (const int*)d_in[5];
    const float* Wl1   = (const float*)d_in[6];
    const float* bl1   = (const float*)d_in[7];
    const float* Wr1   = (const float*)d_in[8];
    const float* br1   = (const float*)d_in[9];
    const float* att1  = (const float*)d_in[10];
    const float* bias1 = (const float*)d_in[11];
    const float* Wl2   = (const float*)d_in[12];
    const float* bl2   = (const float*)d_in[13];
    const float* Wr2   = (const float*)d_in[14];
    const float* br2   = (const float*)d_in[15];
    const float* att2  = (const float*)d_in[16];
    const float* bias2 = (const float*)d_in[17];
    const float* Wc    = (const float*)d_in[18];
    const float* bc    = (const float*)d_in[19];
    float* out = (float*)d_out;

    // workspace layout (~55 MB)
    char* p = (char*)d_ws;
    unsigned short* xb   = (unsigned short*)p; p += (size_t)M_PAD * IN_CH * 2;
    unsigned short* x1b  = (unsigned short*)p; p += (size_t)M_PAD * D1 * 2;
    unsigned char*  xl1b = (unsigned char*)p;  p += (size_t)N_NODES * D1;      // fp8
    unsigned short* xr1b = (unsigned short*)p; p += (size_t)N_NODES * D1 * 2;
    unsigned char*  xl2b = (unsigned char*)p;  p += (size_t)N_NODES * D2;      // fp8
    unsigned short* xr2b = (unsigned short*)p; p += (size_t)N_NODES * D2 * 2;
    unsigned short* wt1l = (unsigned short*)p; p += (size_t)D1 * IN_CH * 2;
    unsigned short* wt1r = (unsigned short*)p; p += (size_t)D1 * IN_CH * 2;
    unsigned short* wt2l = (unsigned short*)p; p += (size_t)D2 * D1 * 2;
    unsigned short* wt2r = (unsigned short*)p; p += (size_t)D2 * D1 * 2;
    int* count      = (int*)p; p += (size_t)N_NODES * 4;
    int* offsets    = (int*)p; p += (size_t)(N_NODES + 4) * 4;
    int* rank       = (int*)p; p += (size_t)ET * 4;
    int* sorted_src = (int*)p; p += (size_t)ET * 4;
    int* cb         = (int*)p; p += (size_t)NB_HIST * N_NODES * 4;  // 10.24 MB

    prep_kernel<<<NB_HIST + WT_BLOCKS + XCONV_BLOCKS, 256, 0, stream>>>(
        gnn_x, Wl1, Wr1, Wl2, Wr2, edge_dst,
        xb, wt1l, wt1r, wt2l, wt2r, cb, rank);
    repprefix_kernel<<<(N_NODES + 255) / 256, 256, 0, stream>>>(cb, count);
    scan_kernel<<<1, 1024, 0, stream>>>(count, offsets);

    // layer-1 dual GEMM + edge scatter (independent; one dispatch)
    gemm1_scatter_kernel<<<G1_BLOCKS + SCAT_BLOCKS, 256, 0, stream>>>(
        xb, wt1l, wt1r, bl1, br1, xl1b, xr1b,
        edge_src, edge_dst, rank, offsets, cb, sorted_src);

    aggregate1_kernel<<<M_PAD / 4, 256, 0, stream>>>(
        xl1b, xr1b, att1, bias1, offsets, sorted_src, x1b);

    // layer 2: 32-col-per-wave dual GEMM (xl2 fp8, xr2 bf16)
    dim3 g2(M_PAD / 64, D2 / 128);   // (313, 2)
    dual_gemm_w32_kernel<D1><<<g2, 256, 0, stream>>>(
        x1b, wt2l, wt2r, bl2, br2, xl2b, xr2b, N_NODES, D2);

    // fused layer-2 aggregation + classifier (one block per pair)
    agg2_classifier_kernel<<<BPAIRS, 256, 0, stream>>>(
        xl2b, xr2b, att2, bias2, offsets, sorted_src,
        vanilla_x, a1_idx, a2_idx, Wc, bc, out);
}